// Round 14
// baseline (163.608 us; speedup 1.0000x reference)
//
#include <hip/hip_runtime.h>

// ConvCaps via MFMA. Per block (b, ho, 8 wo): votes = W[256 oc x 144 k] *
// X_im2col[144 k x 64 n], n = p*8+ci, k = (kh*3+kw)*16 + pi (padded to 160).
// mfma_f32_16x16x32_f16, fp32 accumulate. Prep kernel writes fp16 A-frags
// (80 KB) to d_ws once; blocks stream them from L2.
// R14: WAVES SPLIT M (not N). Wave w owns co in {4w..4w+3}, ALL 64 n:
//   per kt: 4 A-frag global loads (20 KB/wave total, was 80 KB) + 4 B-frag
//   ds_read_b128. Block A-traffic 320->80 KB: kills the ~38us L2 stream.
//   acc[mi][nt]: lane l -> n = nt*16 + (l&15), po = (l>>4)*4 + r,
//   co = 4w+mi. ci = nl&7, p = nt*2 + (nl>>3)  (same lane shapes as R13).
// B-frag = ONE aligned ds_read_b128 from xs[ci][r][c][q] (q innermost,
// per-ci stride 244 words -> 8 ci lanes on 8 banks).
// Staging: one thread per (ci,r,q); 2x float4 + 2 edge scalars.
// Routing (R13-proven, indices rewired):
//   it-0: cij = 1/16 const; bb pure-written.
//   softmax: 1024 items / 256 threads, DPP row_ror; bv = bb0+bb1 slots.
//   ci-sum: DPP 0xB1, 0x4E, 0x141.  q2 po-sum: swz_xor16 + shfl_xor32.
//   uu: swz_xor16 only; g=0/g=2 lanes write pair-partials to 2 bb slots.
//   cw: 4x ds_read_b128 rows ccl[(nt*16+nl)*20 + 4w]. bias hoisted (4xf32x4).
// LDS overlay: shu = xs (GEMM) -> bb0|bb1 (softmax) -> vjlds (it2 out).

namespace {
constexpr int CI = 8, PIn = 16, H = 64, Wd = 64;
constexpr int TP = 8;          // wo pixels per block
constexpr int NQ = 8;          // pi pairs in x patch
constexpr int CIW = 244;       // per-ci stride in h2 units (240 + 4 pad)
constexpr int KT = 5;          // K tiles of 32 (K=160, 144 real)
constexpr int BBO = 1088;      // bb slot offset (64*17)
}

typedef __fp16 h2  __attribute__((ext_vector_type(2)));
typedef __fp16 f16x8 __attribute__((ext_vector_type(8)));
typedef float  f32x4 __attribute__((ext_vector_type(4)));

__device__ __forceinline__ h2 pkh(float a, float b) {
#if __has_builtin(__builtin_amdgcn_cvt_pkrtz)
    return __builtin_amdgcn_cvt_pkrtz(a, b);
#else
    h2 r; r[0] = (__fp16)a; r[1] = (__fp16)b; return r;
#endif
}

template<int CTRL>
__device__ __forceinline__ float dppmovf(float x) {
    return __builtin_bit_cast(float,
        __builtin_amdgcn_mov_dpp(__builtin_bit_cast(int, x), CTRL, 0xf, 0xf, true));
}
template<int CTRL>
__device__ __forceinline__ float dppadd(float x) { return x + dppmovf<CTRL>(x); }

__device__ __forceinline__ float rsum16(float x) {   // over 16-lane row
    x += dppmovf<0x121>(x); x += dppmovf<0x122>(x);
    x += dppmovf<0x124>(x); x += dppmovf<0x128>(x);
    return x;
}
__device__ __forceinline__ float rmax16(float x) {
    x = fmaxf(x, dppmovf<0x121>(x)); x = fmaxf(x, dppmovf<0x122>(x));
    x = fmaxf(x, dppmovf<0x124>(x)); x = fmaxf(x, dppmovf<0x128>(x));
    return x;
}
__device__ __forceinline__ float swz_xor16(float x) {
    return __builtin_bit_cast(float,
        __builtin_amdgcn_ds_swizzle(__builtin_bit_cast(int, x), 0x401F));
}

// ---- prep: conv_w (fp32 OIHW [256][16][3][3]) -> fp16 A-frags in ws ----
// frag f = (kt*16 + m): lane l holds A[oc = m*16 + (l&15)][k = kt*32 + (l>>4)*8 + j]
__global__ __launch_bounds__(256)
void prep_wfrag(const float* __restrict__ w, __fp16* __restrict__ wf) {
    const int gid = blockIdx.x * 256 + threadIdx.x;
    if (gid >= KT * 16 * 64) return;
    const int l = gid & 63, m = (gid >> 6) & 15, kt = gid >> 10;
    const int oc = m * 16 + (l & 15);
    h2* dp = reinterpret_cast<h2*>(wf + (size_t)gid * 8);
    #pragma unroll
    for (int jw = 0; jw < 4; ++jw) {
        const int k0 = kt * 32 + (l >> 4) * 8 + jw * 2;
        float f0 = 0.f, f1 = 0.f;
        if (k0 < 144)     f0 = w[oc * 144 + (k0 & 15) * 9 + (k0 >> 4)];
        if (k0 + 1 < 144) f1 = w[oc * 144 + ((k0 + 1) & 15) * 9 + ((k0 + 1) >> 4)];
        dp[jw] = pkh(f0, f1);
    }
}

__global__ __launch_bounds__(256, 5)
void convcaps_mfma(const float* __restrict__ x,
                   const __fp16* __restrict__ wf,
                   const float* __restrict__ biases,
                   const int* __restrict__ routings_p,
                   float* __restrict__ out)
{
    const int t    = threadIdx.x;
    const int lane = t & 63;
    const int wv   = t >> 6;          // wave = M-quad: co in {4wv..4wv+3}
    const int g    = lane >> 4;       // 0..3 (po group)
    const int nl   = lane & 15;
    const int ci_  = nl & 7;          // ci for this lane (all nt)
    const int pb   = nl >> 3;         // p = nt*2 + pb
    const int gh   = g >> 1;          // r9 = 2*kt + gh
    const int ql   = (g & 1) * 4;     // q base for B-frag

    const int blk  = (blockIdx.x & 7) * 512 + (blockIdx.x >> 3);
    const int wseg = blk & 7;
    const int ho   = (blk >> 3) & 63;
    const int b    = blk >> 9;
    const int wo0  = wseg * TP;
    const int routings = routings_p[0];

    // shu overlay: xs (staging+GEMM) -> bb0|bb1 (softmax) -> vjlds (it2 out)
    __shared__ float  shu[2816];                  // 11264 B
    alignas(16) __shared__ float ccl[64 * 20];    // 5120 B cij [n][co] stride 20
    alignas(16) __shared__ float bl[256];         // biases
    h2*    xs    = reinterpret_cast<h2*>(shu);    // [ci][r][c][q], CIW words/ci
    float* bb    = shu;                           // bij partials: [slot][n*17+co]
    float* vjlds = shu;                           // [oc][p] stride 11

    // ---- stage x patch: one thread per (ci, r, q); 2x float4 + 2 edges ----
    if (t < 192) {
        const int ci  = t / 24;
        const int rem = t - ci * 24;
        const int r   = rem >> 3, q = rem & 7;
        const int hy  = ho - 1 + r;
        const bool rowok = (hy >= 0) && (hy < H);
        const float* row0 = x + (((size_t)(b * CI + ci) * PIn + 2 * q) * H + hy) * Wd;
        const float* row1 = row0 + H * Wd;
        float4 m0a = {0,0,0,0}, m1a = {0,0,0,0}, m0b = {0,0,0,0}, m1b = {0,0,0,0};
        float  e0a = 0.f, e0b = 0.f, e9a = 0.f, e9b = 0.f;
        if (rowok) {
            m0a = *reinterpret_cast<const float4*>(row0 + wo0);
            m1a = *reinterpret_cast<const float4*>(row0 + wo0 + 4);
            m0b = *reinterpret_cast<const float4*>(row1 + wo0);
            m1b = *reinterpret_cast<const float4*>(row1 + wo0 + 4);
            if (wo0 > 0)       { e0a = row0[wo0 - 1]; e0b = row1[wo0 - 1]; }
            if (wo0 + 8 < Wd)  { e9a = row0[wo0 + 8]; e9b = row1[wo0 + 8]; }
        }
        h2* xr = &xs[ci * CIW + (r * 10) * 8 + q];   // c stride = 8 h2 units
        xr[0 * 8] = pkh(e0a, e0b);
        xr[1 * 8] = pkh(m0a.x, m0b.x);
        xr[2 * 8] = pkh(m0a.y, m0b.y);
        xr[3 * 8] = pkh(m0a.z, m0b.z);
        xr[4 * 8] = pkh(m0a.w, m0b.w);
        xr[5 * 8] = pkh(m1a.x, m1b.x);
        xr[6 * 8] = pkh(m1a.y, m1b.y);
        xr[7 * 8] = pkh(m1a.z, m1b.z);
        xr[8 * 8] = pkh(m1a.w, m1b.w);
        xr[9 * 8] = pkh(e9a, e9b);
    }
    bl[t] = biases[t];
    __syncthreads();

    // ---- GEMM: acc[mi][nt] = votes[oc=(4wv+mi)*16+po][n=nt*16+nl] ----
    f32x4 acc[4][4];
    #pragma unroll
    for (int mi = 0; mi < 4; ++mi)
        #pragma unroll
        for (int nt = 0; nt < 4; ++nt) acc[mi][nt] = f32x4{0.f, 0.f, 0.f, 0.f};

    const f16x8* ap = reinterpret_cast<const f16x8*>(wf);
    #pragma unroll
    for (int kt = 0; kt < KT; ++kt) {
        f16x8 bfr[4];
        const int k0 = kt * 32 + g * 8;
        if (k0 < 144) {
            const int r9 = 2 * kt + gh;
            const int kh = (r9 * 11) >> 5;        // r9/3 for r9<=8
            const int kw = r9 - 3 * kh;
            const int base = ci_ * CIW + (kh * 10 + pb + kw) * 8 + ql;
            #pragma unroll
            for (int nt = 0; nt < 4; ++nt)
                bfr[nt] = *reinterpret_cast<const f16x8*>(&xs[base + nt * 16]); // p += 2
        } else {
            #pragma unroll
            for (int nt = 0; nt < 4; ++nt)
                bfr[nt] = f16x8{(__fp16)0.f, (__fp16)0.f, (__fp16)0.f, (__fp16)0.f,
                                (__fp16)0.f, (__fp16)0.f, (__fp16)0.f, (__fp16)0.f};
        }
        #pragma unroll
        for (int mi = 0; mi < 4; ++mi) {
            const f16x8 afrag = ap[(kt * 16 + wv * 4 + mi) * 64 + lane];
            #pragma unroll
            for (int nt = 0; nt < 4; ++nt)
                acc[mi][nt] = __builtin_amdgcn_mfma_f32_16x16x32_f16(
                                  afrag, bfr[nt], acc[mi][nt], 0, 0, 0);
        }
    }

    // hoist biases: bias4[mi] = bl[(4wv+mi)*16 + g*4 .. +3]
    f32x4 bias4[4];
    #pragma unroll
    for (int mi = 0; mi < 4; ++mi)
        bias4[mi] = *reinterpret_cast<const f32x4*>(&bl[(wv * 4 + mi) * 16 + g * 4]);
    __syncthreads();   // xs dead; shu region becomes bb (then vjlds in it2)

    // ---- routing in MFMA layout; it-0 shortcut (cij = 1/16) ----
    for (int it = 0; it < routings; ++it) {
        const bool first  = (it == 0);
        const bool lastit = (it + 1 >= routings);

        f32x4 cw4[4];
        if (!first) {
            // softmax over co: 1024 items, item i -> row=i>>4 (= n), co=i&15
            #pragma unroll
            for (int k2 = 0; k2 < 4; ++k2) {
                const int i   = t + 256 * k2;
                const int idx = (i >> 4) * 17 + (i & 15);
                const float bv = bb[idx] + bb[BBO + idx];   // sum g01 + g23
                const float mx = rmax16(bv);
                const float e  = __expf(bv - mx);
                const float sd = rsum16(e);
                ccl[(i >> 4) * 20 + (i & 15)] = e * __builtin_amdgcn_rcpf(sd);
            }
            __syncthreads();   // after this, bb is dead in lastit -> vjlds ok
            #pragma unroll
            for (int nt = 0; nt < 4; ++nt)
                cw4[nt] = *reinterpret_cast<const f32x4*>(
                              &ccl[(nt * 16 + nl) * 20 + wv * 4]);
        }

        #pragma unroll
        for (int mi = 0; mi < 4; ++mi) {
            #pragma unroll
            for (int nt = 0; nt < 4; ++nt) {
                const float cw = first ? 0.0625f : cw4[nt][mi];
                float s0 = cw * acc[mi][nt][0], s1 = cw * acc[mi][nt][1];
                float s2 = cw * acc[mi][nt][2], s3 = cw * acc[mi][nt][3];
                // sum over ci (lane bits 0..2)
                s0 = dppadd<0xB1>(s0);  s1 = dppadd<0xB1>(s1);
                s2 = dppadd<0xB1>(s2);  s3 = dppadd<0xB1>(s3);
                s0 = dppadd<0x4E>(s0);  s1 = dppadd<0x4E>(s1);
                s2 = dppadd<0x4E>(s2);  s3 = dppadd<0x4E>(s3);
                s0 = dppadd<0x141>(s0); s1 = dppadd<0x141>(s1);
                s2 = dppadd<0x141>(s2); s3 = dppadd<0x141>(s3);
                s0 += bias4[mi][0]; s1 += bias4[mi][1];
                s2 += bias4[mi][2]; s3 += bias4[mi][3];
                // squash: n2 over po = 4 local r + xor16 + xor32
                float q2 = s0 * s0 + s1 * s1 + s2 * s2 + s3 * s3;
                q2 += swz_xor16(q2);
                q2 += __shfl_xor(q2, 32, 64);
                const float sc = __fsqrt_rn(q2) * __builtin_amdgcn_rcpf(1.f + q2);
                const float v0 = s0 * sc, v1 = s1 * sc, v2 = s2 * sc, v3 = s3 * sc;
                if (!lastit) {
                    float uu = acc[mi][nt][0] * v0 + acc[mi][nt][1] * v1
                             + acc[mi][nt][2] * v2 + acc[mi][nt][3] * v3;
                    uu += swz_xor16(uu);      // pair partial: (g0+g1) | (g2+g3)
                    if ((g & 1) == 0) {       // g=0 -> slot 0, g=2 -> slot 1
                        const int idx = (g << 9) + (g << 5)
                                      + (nt * 16 + nl) * 17 + wv * 4 + mi;
                        if (first) bb[idx] = uu;   // bij was 0
                        else       bb[idx] += uu;
                    }
                } else if (ci_ == 0) {
                    const int oc = (wv * 4 + mi) * 16 + g * 4;
                    const int p  = nt * 2 + pb;
                    vjlds[(oc + 0) * 11 + p] = v0;
                    vjlds[(oc + 1) * 11 + p] = v1;
                    vjlds[(oc + 2) * 11 + p] = v2;
                    vjlds[(oc + 3) * 11 + p] = v3;
                }
            }
        }
        __syncthreads();
    }

    // ---- dense output: thread t = oc, 8 wo ----
    float o[8];
    #pragma unroll
    for (int j = 0; j < 8; ++j) o[j] = vjlds[t * 11 + j];
    float* op = out + ((size_t)(b * 256 + t)) * (H * Wd) + ho * Wd + wo0;
    *reinterpret_cast<float4*>(op)     = make_float4(o[0], o[1], o[2], o[3]);
    *reinterpret_cast<float4*>(op + 4) = make_float4(o[4], o[5], o[6], o[7]);
}

extern "C" void kernel_launch(void* const* d_in, const int* in_sizes, int n_in,
                              void* d_out, int out_size, void* d_ws, size_t ws_size,
                              hipStream_t stream) {
    const float* x       = (const float*)d_in[0];
    const float* w       = (const float*)d_in[1];
    const float* biases  = (const float*)d_in[2];
    const int*   routing = (const int*)d_in[3];
    float* out = (float*)d_out;
    __fp16* wf = (__fp16*)d_ws;   // needs 81920 B

    hipLaunchKernelGGL(prep_wfrag, dim3(20), dim3(256), 0, stream, w, wf);
    hipLaunchKernelGGL(convcaps_mfma, dim3(8 * 64 * (64 / TP)), dim3(256), 0, stream,
                       x, wf, biases, routing, out);
}

// Round 15
// 127.490 us; speedup vs baseline: 1.2833x; 1.2833x over previous
//
#include <hip/hip_runtime.h>

// ConvCaps via MFMA: per block (b, ho, 8 wo), votes = W[256 oc x 144 k] *
// X_im2col[144 k x 64 n], n = p*8+ci, k = (kh*3+kw)*16 + pi (padded to 160).
// mfma_f32_16x16x32_f16, fp32 accumulate. Prep kernel writes fp16 A-frags
// (80 KB) to d_ws once per call; all blocks stream them from L2.
// WAVE = N-TILE (R14 LESSON: waves splitting M regressed 28% — all 4 waves
// reading the SAME A-frags in the same order makes L1 a free broadcast;
// disjoint per-wave A-streams collapsed cache hit rate, FETCH 14->51 MB).
// B-frag = ONE aligned ds_read_b128 from xs: layout xs[ci][r][c][q] (q = pi
// pair innermost, h2 units), per-ci stride 244 words (%32=20 -> 8 ci lanes
// hit 8 distinct banks).
// Staging: one thread per (ci,r,q) unit; 2x float4 + 2 edge scalars.
// Routing in MFMA C-layout: lane=(p,ci), regs=[co=m][po=g*4+r].
//   it-0 shortcut: cij = 1/16 const; bb pure-written (no init).
//   softmax (it>=1): 1024 items over 256 threads, DPP row_ror reduces;
//     bv = bb0 + bb1 (two partial slots, see below).
//   ci-sum: DPP quad_perm xor1 (0xB1), xor2 (0x4E), half-mirror (0x141)
//   q2 po-sum: ds_swizzle xor16 (0x401F) + __shfl_xor 32  [permlane*_swap
//     REFUTED on HW twice: R11/R12 absmax 0.54 identical]
//   uu po-sum: swz_xor16 ONLY; lanes g=0 and g=2 write their pair-partials
//     to bb0/bb1 — softmax sums them (saves the xor32 hop, bit-identical).
//   ccl: stride 20 words (80B rows, 16B-aligned) -> cij read as 4x
//     ds_read_b128 instead of 16x b32.
// LDS overlay: shu = xs (GEMM) -> bb0|bb1 (softmax) -> vjlds (it2 out).
// Occupancy note: acc 64 AGPR + 48 VGPR = 112 regs/wave -> hard cap
// 4 waves/SIMD (~50%); this is the design's structural occupancy limit.

namespace {
constexpr int CI = 8, PIn = 16, H = 64, Wd = 64;
constexpr int TP = 8;          // wo pixels per block
constexpr int NQ = 8;          // pi pairs in x patch
constexpr int CIW = 244;       // per-ci stride in h2 units (3*10*8=240 + 4 pad)
constexpr int KT = 5;          // K tiles of 32 (K=160, 144 real)
constexpr int BBO = 1088;      // bb slot offset (64*17)
}

typedef __fp16 h2  __attribute__((ext_vector_type(2)));
typedef __fp16 f16x8 __attribute__((ext_vector_type(8)));
typedef float  f32x4 __attribute__((ext_vector_type(4)));

__device__ __forceinline__ h2 pkh(float a, float b) {
#if __has_builtin(__builtin_amdgcn_cvt_pkrtz)
    return __builtin_amdgcn_cvt_pkrtz(a, b);
#else
    h2 r; r[0] = (__fp16)a; r[1] = (__fp16)b; return r;
#endif
}

template<int CTRL>
__device__ __forceinline__ float dppmovf(float x) {
    return __builtin_bit_cast(float,
        __builtin_amdgcn_mov_dpp(__builtin_bit_cast(int, x), CTRL, 0xf, 0xf, true));
}
template<int CTRL>
__device__ __forceinline__ float dppadd(float x) { return x + dppmovf<CTRL>(x); }

__device__ __forceinline__ float rsum16(float x) {   // over 16-lane row
    x += dppmovf<0x121>(x); x += dppmovf<0x122>(x);
    x += dppmovf<0x124>(x); x += dppmovf<0x128>(x);
    return x;
}
__device__ __forceinline__ float rmax16(float x) {
    x = fmaxf(x, dppmovf<0x121>(x)); x = fmaxf(x, dppmovf<0x122>(x));
    x = fmaxf(x, dppmovf<0x124>(x)); x = fmaxf(x, dppmovf<0x128>(x));
    return x;
}
__device__ __forceinline__ float swz_xor16(float x) {
    return __builtin_bit_cast(float,
        __builtin_amdgcn_ds_swizzle(__builtin_bit_cast(int, x), 0x401F));
}

// ---- prep: conv_w (fp32 OIHW [256][16][3][3]) -> fp16 A-frags in ws ----
// frag f = (kt*16 + m): lane l holds A[oc = m*16 + (l&15)][k = kt*32 + (l>>4)*8 + j]
__global__ __launch_bounds__(256)
void prep_wfrag(const float* __restrict__ w, __fp16* __restrict__ wf) {
    const int gid = blockIdx.x * 256 + threadIdx.x;
    if (gid >= KT * 16 * 64) return;
    const int l = gid & 63, m = (gid >> 6) & 15, kt = gid >> 10;
    const int oc = m * 16 + (l & 15);
    h2* dp = reinterpret_cast<h2*>(wf + (size_t)gid * 8);
    #pragma unroll
    for (int jw = 0; jw < 4; ++jw) {
        const int k0 = kt * 32 + (l >> 4) * 8 + jw * 2;
        float f0 = 0.f, f1 = 0.f;
        if (k0 < 144)     f0 = w[oc * 144 + (k0 & 15) * 9 + (k0 >> 4)];
        if (k0 + 1 < 144) f1 = w[oc * 144 + ((k0 + 1) & 15) * 9 + ((k0 + 1) >> 4)];
        dp[jw] = pkh(f0, f1);
    }
}

__global__ __launch_bounds__(256, 5)
void convcaps_mfma(const float* __restrict__ x,
                   const __fp16* __restrict__ wf,
                   const float* __restrict__ biases,
                   const int* __restrict__ routings_p,
                   float* __restrict__ out)
{
    const int t    = threadIdx.x;
    const int lane = t & 63;
    const int wv   = t >> 6;          // wave = ntile
    const int g    = lane >> 4;       // 0..3
    const int nl   = lane & 15;
    const int n    = wv * 16 + nl;    // 0..63 = p*8 + ci
    const int p_   = n >> 3, ci_ = n & 7;
    const int gh   = g >> 1;          // r9 = 2*kt + gh
    const int ql   = (g & 1) * 4;     // q base for B-frag

    const int blk  = (blockIdx.x & 7) * 512 + (blockIdx.x >> 3);
    const int wseg = blk & 7;
    const int ho   = (blk >> 3) & 63;
    const int b    = blk >> 9;
    const int wo0  = wseg * TP;
    const int routings = routings_p[0];

    // shu overlay: xs (staging+GEMM) -> bb0|bb1 (softmax) -> vjlds (it2 out)
    __shared__ float  shu[2816];                  // 11264 B
    alignas(16) __shared__ float ccl[64 * 20];    // 5120 B cij [n][co] stride 20
    __shared__ float  bl[256];                    // biases
    h2*    xs    = reinterpret_cast<h2*>(shu);    // [ci][r][c][q], CIW words/ci
    float* bb    = shu;                           // bij partials: [slot][n*17+m]
    float* vjlds = shu;                           // [oc][p] stride 11

    // ---- stage x patch: one thread per (ci, r, q); 2x float4 + 2 edges ----
    if (t < 192) {
        const int ci  = t / 24;
        const int rem = t - ci * 24;
        const int r   = rem >> 3, q = rem & 7;
        const int hy  = ho - 1 + r;
        const bool rowok = (hy >= 0) && (hy < H);
        const float* row0 = x + (((size_t)(b * CI + ci) * PIn + 2 * q) * H + hy) * Wd;
        const float* row1 = row0 + H * Wd;
        float4 m0a = {0,0,0,0}, m1a = {0,0,0,0}, m0b = {0,0,0,0}, m1b = {0,0,0,0};
        float  e0a = 0.f, e0b = 0.f, e9a = 0.f, e9b = 0.f;
        if (rowok) {
            m0a = *reinterpret_cast<const float4*>(row0 + wo0);
            m1a = *reinterpret_cast<const float4*>(row0 + wo0 + 4);
            m0b = *reinterpret_cast<const float4*>(row1 + wo0);
            m1b = *reinterpret_cast<const float4*>(row1 + wo0 + 4);
            if (wo0 > 0)       { e0a = row0[wo0 - 1]; e0b = row1[wo0 - 1]; }
            if (wo0 + 8 < Wd)  { e9a = row0[wo0 + 8]; e9b = row1[wo0 + 8]; }
        }
        h2* xr = &xs[ci * CIW + (r * 10) * 8 + q];   // c stride = 8 h2 units
        xr[0 * 8] = pkh(e0a, e0b);
        xr[1 * 8] = pkh(m0a.x, m0b.x);
        xr[2 * 8] = pkh(m0a.y, m0b.y);
        xr[3 * 8] = pkh(m0a.z, m0b.z);
        xr[4 * 8] = pkh(m0a.w, m0b.w);
        xr[5 * 8] = pkh(m1a.x, m1b.x);
        xr[6 * 8] = pkh(m1a.y, m1b.y);
        xr[7 * 8] = pkh(m1a.z, m1b.z);
        xr[8 * 8] = pkh(m1a.w, m1b.w);
        xr[9 * 8] = pkh(e9a, e9b);
    }
    bl[t] = biases[t];
    __syncthreads();

    // ---- GEMM: acc[m] = votes[oc = m*16+g*4+r][n]; B = one b128 from xs ----
    f32x4 acc[16];
    #pragma unroll
    for (int m = 0; m < 16; ++m) acc[m] = f32x4{0.f, 0.f, 0.f, 0.f};

    const f16x8* ap = reinterpret_cast<const f16x8*>(wf);
    #pragma unroll
    for (int kt = 0; kt < KT; ++kt) {
        f16x8 bfrag;
        const int k0 = kt * 32 + g * 8;
        if (k0 < 144) {
            const int r9 = 2 * kt + gh;
            const int kh = (r9 * 11) >> 5;        // r9/3 for r9<=8
            const int kw = r9 - 3 * kh;
            bfrag = *reinterpret_cast<const f16x8*>(
                &xs[ci_ * CIW + (kh * 10 + p_ + kw) * 8 + ql]);
        } else {
            bfrag = f16x8{(__fp16)0.f, (__fp16)0.f, (__fp16)0.f, (__fp16)0.f,
                          (__fp16)0.f, (__fp16)0.f, (__fp16)0.f, (__fp16)0.f};
        }
        #pragma unroll
        for (int m = 0; m < 16; ++m) {
            const f16x8 afrag = ap[(kt * 16 + m) * 64 + lane];
            acc[m] = __builtin_amdgcn_mfma_f32_16x16x32_f16(afrag, bfrag, acc[m], 0, 0, 0);
        }
    }
    __syncthreads();   // xs dead; shu region becomes bb (then vjlds in it2)

    // ---- routing in MFMA layout; it-0 shortcut (cij = 1/16) ----
    for (int it = 0; it < routings; ++it) {
        const bool first  = (it == 0);
        const bool lastit = (it + 1 >= routings);

        f32x4 cw4[4];
        if (!first) {
            // softmax over co: 1024 items, item i -> row=i>>4 (= n), co=i&15
            #pragma unroll
            for (int k2 = 0; k2 < 4; ++k2) {
                const int i   = t + 256 * k2;
                const int idx = (i >> 4) * 17 + (i & 15);
                const float bv = bb[idx] + bb[BBO + idx];   // sum g01 + g23
                const float mx = rmax16(bv);
                const float e  = __expf(bv - mx);
                const float sd = rsum16(e);
                ccl[(i >> 4) * 20 + (i & 15)] = e * __builtin_amdgcn_rcpf(sd);
            }
            __syncthreads();   // after this, bb is dead in lastit -> vjlds ok
            const f32x4* cwp = reinterpret_cast<const f32x4*>(&ccl[n * 20]);
            cw4[0] = cwp[0]; cw4[1] = cwp[1]; cw4[2] = cwp[2]; cw4[3] = cwp[3];
        }

        #pragma unroll
        for (int m = 0; m < 16; ++m) {
            const float cw = first ? 0.0625f : cw4[m >> 2][m & 3];
            float s0 = cw * acc[m][0], s1 = cw * acc[m][1];
            float s2 = cw * acc[m][2], s3 = cw * acc[m][3];
            // sum over ci (lane bits 0..2): xor1, xor2, half-mirror
            s0 = dppadd<0xB1>(s0);  s1 = dppadd<0xB1>(s1);
            s2 = dppadd<0xB1>(s2);  s3 = dppadd<0xB1>(s3);
            s0 = dppadd<0x4E>(s0);  s1 = dppadd<0x4E>(s1);
            s2 = dppadd<0x4E>(s2);  s3 = dppadd<0x4E>(s3);
            s0 = dppadd<0x141>(s0); s1 = dppadd<0x141>(s1);
            s2 = dppadd<0x141>(s2); s3 = dppadd<0x141>(s3);
            const f32x4 b4 = *reinterpret_cast<const f32x4*>(&bl[m * 16 + g * 4]);
            s0 += b4[0]; s1 += b4[1]; s2 += b4[2]; s3 += b4[3];
            // squash: n2 over po = 4 local r + xor16 + xor32 (R10-proven)
            float q2 = s0 * s0 + s1 * s1 + s2 * s2 + s3 * s3;
            q2 += swz_xor16(q2);
            q2 += __shfl_xor(q2, 32, 64);
            const float sc = __fsqrt_rn(q2) * __builtin_amdgcn_rcpf(1.f + q2);
            const float v0 = s0 * sc, v1 = s1 * sc, v2 = s2 * sc, v3 = s3 * sc;
            if (!lastit) {
                float uu = acc[m][0] * v0 + acc[m][1] * v1
                         + acc[m][2] * v2 + acc[m][3] * v3;
                uu += swz_xor16(uu);          // pair partial: (g0+g1) | (g2+g3)
                if ((g & 1) == 0) {           // g=0 -> slot 0, g=2 -> slot 1
                    const int idx = (g << 9) + (g << 5) + n * 17 + m; // g/2*1088
                    if (first) bb[idx] = uu;  // bij was 0
                    else       bb[idx] += uu;
                }
            } else if (ci_ == 0) {
                const int oc = m * 16 + g * 4;
                vjlds[(oc + 0) * 11 + p_] = v0;
                vjlds[(oc + 1) * 11 + p_] = v1;
                vjlds[(oc + 2) * 11 + p_] = v2;
                vjlds[(oc + 3) * 11 + p_] = v3;
            }
        }
        __syncthreads();
    }

    // ---- dense output: thread t = oc, 8 wo ----
    float o[8];
    #pragma unroll
    for (int j = 0; j < 8; ++j) o[j] = vjlds[t * 11 + j];
    float* op = out + ((size_t)(b * 256 + t)) * (H * Wd) + ho * Wd + wo0;
    *reinterpret_cast<float4*>(op)     = make_float4(o[0], o[1], o[2], o[3]);
    *reinterpret_cast<float4*>(op + 4) = make_float4(o[4], o[5], o[6], o[7]);
}

extern "C" void kernel_launch(void* const* d_in, const int* in_sizes, int n_in,
                              void* d_out, int out_size, void* d_ws, size_t ws_size,
                              hipStream_t stream) {
    const float* x       = (const float*)d_in[0];
    const float* w       = (const float*)d_in[1];
    const float* biases  = (const float*)d_in[2];
    const int*   routing = (const int*)d_in[3];
    float* out = (float*)d_out;
    __fp16* wf = (__fp16*)d_ws;   // needs 81920 B

    hipLaunchKernelGGL(prep_wfrag, dim3(20), dim3(256), 0, stream, w, wf);
    hipLaunchKernelGGL(convcaps_mfma, dim3(8 * 64 * (64 / TP)), dim3(256), 0, stream,
                       x, wf, biases, routing, out);
}

// Round 16
// 109.188 us; speedup vs baseline: 1.4984x; 1.1676x over previous
//
#include <hip/hip_runtime.h>

// ConvCaps via MFMA: per block (b, ho, 8 wo), votes = W[256 oc x 144 k] *
// X_im2col[144 k x 64 n], n = p*8+ci, k = (kh*3+kw)*16 + pi (padded to 160).
// mfma_f32_16x16x32_f16, fp32 accumulate. Prep kernel writes fp16 A-frags
// (80 KB) to d_ws once per call; all blocks stream them from L2.
// WAVE = N-TILE (R14 LESSON: waves splitting M regressed 28% — all 4 waves
// reading the SAME A-frags makes L1 a free broadcast).
// B-frag = ONE aligned ds_read_b128 from xs: layout xs[ci][r][c][q] (q = pi
// pair innermost, h2 units), per-ci stride 244 words -> 8 ci lanes, 8 banks.
// Staging: one thread per (ci,r,q) unit; 2x float4 + 2 edge scalars.
// Routing in MFMA C-layout: lane=(p,ci), regs=[co=m][po=g*4+r].
//   it-0 shortcut: cij = 1/16 const; bb pure-written (no init).
//   softmax (it>=1): 1024 items over 256 threads, DPP row_ror reduces;
//     bv = bb0 + bb1 (two partial slots).
//   ci-sum: DPP quad_perm xor1 (0xB1), xor2 (0x4E), half-mirror (0x141)
//   q2 po-sum: ds_swizzle xor16 (0x401F) + __shfl_xor 32  [permlane*_swap
//     REFUTED on HW twice: R11/R12 absmax 0.54 identical]
//   uu po-sum: swz_xor16 ONLY; g=0/g=2 lanes write pair-partials to
//     bb0/bb1 — softmax sums them (bit-identical, saves xor32 hop).
//   ccl: stride 20 (80B rows) -> cij read as 4x ds_read_b128.
// R16: (a) __launch_bounds__(256,4) — the old (256,5) capped VGPR at 48
//   for an unreachable 5-wave target (64 AGPR makes it 4 waves max);
//   (256,4) gives the scheduler VGPR slack to interleave m-chains.
//   (b) routings==3 specialization: fully unrolled iteration sequence with
//   compile-time first/last flags (runtime-bounded loop kept as fallback).
// LDS overlay: shu = xs (GEMM) -> bb0|bb1 (softmax) -> vjlds (last-it out).

namespace {
constexpr int CI = 8, PIn = 16, H = 64, Wd = 64;
constexpr int TP = 8;          // wo pixels per block
constexpr int NQ = 8;          // pi pairs in x patch
constexpr int CIW = 244;       // per-ci stride in h2 units (3*10*8=240 + 4 pad)
constexpr int KT = 5;          // K tiles of 32 (K=160, 144 real)
constexpr int BBO = 1088;      // bb slot offset (64*17)
}

typedef __fp16 h2  __attribute__((ext_vector_type(2)));
typedef __fp16 f16x8 __attribute__((ext_vector_type(8)));
typedef float  f32x4 __attribute__((ext_vector_type(4)));

__device__ __forceinline__ h2 pkh(float a, float b) {
#if __has_builtin(__builtin_amdgcn_cvt_pkrtz)
    return __builtin_amdgcn_cvt_pkrtz(a, b);
#else
    h2 r; r[0] = (__fp16)a; r[1] = (__fp16)b; return r;
#endif
}

template<int CTRL>
__device__ __forceinline__ float dppmovf(float x) {
    return __builtin_bit_cast(float,
        __builtin_amdgcn_mov_dpp(__builtin_bit_cast(int, x), CTRL, 0xf, 0xf, true));
}
template<int CTRL>
__device__ __forceinline__ float dppadd(float x) { return x + dppmovf<CTRL>(x); }

__device__ __forceinline__ float rsum16(float x) {   // over 16-lane row
    x += dppmovf<0x121>(x); x += dppmovf<0x122>(x);
    x += dppmovf<0x124>(x); x += dppmovf<0x128>(x);
    return x;
}
__device__ __forceinline__ float rmax16(float x) {
    x = fmaxf(x, dppmovf<0x121>(x)); x = fmaxf(x, dppmovf<0x122>(x));
    x = fmaxf(x, dppmovf<0x124>(x)); x = fmaxf(x, dppmovf<0x128>(x));
    return x;
}
__device__ __forceinline__ float swz_xor16(float x) {
    return __builtin_bit_cast(float,
        __builtin_amdgcn_ds_swizzle(__builtin_bit_cast(int, x), 0x401F));
}

// ---- prep: conv_w (fp32 OIHW [256][16][3][3]) -> fp16 A-frags in ws ----
// frag f = (kt*16 + m): lane l holds A[oc = m*16 + (l&15)][k = kt*32 + (l>>4)*8 + j]
__global__ __launch_bounds__(256)
void prep_wfrag(const float* __restrict__ w, __fp16* __restrict__ wf) {
    const int gid = blockIdx.x * 256 + threadIdx.x;
    if (gid >= KT * 16 * 64) return;
    const int l = gid & 63, m = (gid >> 6) & 15, kt = gid >> 10;
    const int oc = m * 16 + (l & 15);
    h2* dp = reinterpret_cast<h2*>(wf + (size_t)gid * 8);
    #pragma unroll
    for (int jw = 0; jw < 4; ++jw) {
        const int k0 = kt * 32 + (l >> 4) * 8 + jw * 2;
        float f0 = 0.f, f1 = 0.f;
        if (k0 < 144)     f0 = w[oc * 144 + (k0 & 15) * 9 + (k0 >> 4)];
        if (k0 + 1 < 144) f1 = w[oc * 144 + ((k0 + 1) & 15) * 9 + ((k0 + 1) >> 4)];
        dp[jw] = pkh(f0, f1);
    }
}

__global__ __launch_bounds__(256, 4)
void convcaps_mfma(const float* __restrict__ x,
                   const __fp16* __restrict__ wf,
                   const float* __restrict__ biases,
                   const int* __restrict__ routings_p,
                   float* __restrict__ out)
{
    const int t    = threadIdx.x;
    const int lane = t & 63;
    const int wv   = t >> 6;          // wave = ntile
    const int g    = lane >> 4;       // 0..3
    const int nl   = lane & 15;
    const int n    = wv * 16 + nl;    // 0..63 = p*8 + ci
    const int p_   = n >> 3, ci_ = n & 7;
    const int gh   = g >> 1;          // r9 = 2*kt + gh
    const int ql   = (g & 1) * 4;     // q base for B-frag

    const int blk  = (blockIdx.x & 7) * 512 + (blockIdx.x >> 3);
    const int wseg = blk & 7;
    const int ho   = (blk >> 3) & 63;
    const int b    = blk >> 9;
    const int wo0  = wseg * TP;
    const int routings = routings_p[0];

    // shu overlay: xs (staging+GEMM) -> bb0|bb1 (softmax) -> vjlds (last-it out)
    __shared__ float  shu[2816];                  // 11264 B
    alignas(16) __shared__ float ccl[64 * 20];    // 5120 B cij [n][co] stride 20
    __shared__ float  bl[256];                    // biases
    h2*    xs    = reinterpret_cast<h2*>(shu);    // [ci][r][c][q], CIW words/ci
    float* bb    = shu;                           // bij partials: [slot][n*17+m]
    float* vjlds = shu;                           // [oc][p] stride 11

    // ---- stage x patch: one thread per (ci, r, q); 2x float4 + 2 edges ----
    if (t < 192) {
        const int ci  = t / 24;
        const int rem = t - ci * 24;
        const int r   = rem >> 3, q = rem & 7;
        const int hy  = ho - 1 + r;
        const bool rowok = (hy >= 0) && (hy < H);
        const float* row0 = x + (((size_t)(b * CI + ci) * PIn + 2 * q) * H + hy) * Wd;
        const float* row1 = row0 + H * Wd;
        float4 m0a = {0,0,0,0}, m1a = {0,0,0,0}, m0b = {0,0,0,0}, m1b = {0,0,0,0};
        float  e0a = 0.f, e0b = 0.f, e9a = 0.f, e9b = 0.f;
        if (rowok) {
            m0a = *reinterpret_cast<const float4*>(row0 + wo0);
            m1a = *reinterpret_cast<const float4*>(row0 + wo0 + 4);
            m0b = *reinterpret_cast<const float4*>(row1 + wo0);
            m1b = *reinterpret_cast<const float4*>(row1 + wo0 + 4);
            if (wo0 > 0)       { e0a = row0[wo0 - 1]; e0b = row1[wo0 - 1]; }
            if (wo0 + 8 < Wd)  { e9a = row0[wo0 + 8]; e9b = row1[wo0 + 8]; }
        }
        h2* xr = &xs[ci * CIW + (r * 10) * 8 + q];   // c stride = 8 h2 units
        xr[0 * 8] = pkh(e0a, e0b);
        xr[1 * 8] = pkh(m0a.x, m0b.x);
        xr[2 * 8] = pkh(m0a.y, m0b.y);
        xr[3 * 8] = pkh(m0a.z, m0b.z);
        xr[4 * 8] = pkh(m0a.w, m0b.w);
        xr[5 * 8] = pkh(m1a.x, m1b.x);
        xr[6 * 8] = pkh(m1a.y, m1b.y);
        xr[7 * 8] = pkh(m1a.z, m1b.z);
        xr[8 * 8] = pkh(m1a.w, m1b.w);
        xr[9 * 8] = pkh(e9a, e9b);
    }
    bl[t] = biases[t];
    __syncthreads();

    // ---- GEMM: acc[m] = votes[oc = m*16+g*4+r][n]; B = one b128 from xs ----
    f32x4 acc[16];
    #pragma unroll
    for (int m = 0; m < 16; ++m) acc[m] = f32x4{0.f, 0.f, 0.f, 0.f};

    const f16x8* ap = reinterpret_cast<const f16x8*>(wf);
    #pragma unroll
    for (int kt = 0; kt < KT; ++kt) {
        f16x8 bfrag;
        const int k0 = kt * 32 + g * 8;
        if (k0 < 144) {
            const int r9 = 2 * kt + gh;
            const int kh = (r9 * 11) >> 5;        // r9/3 for r9<=8
            const int kw = r9 - 3 * kh;
            bfrag = *reinterpret_cast<const f16x8*>(
                &xs[ci_ * CIW + (kh * 10 + p_ + kw) * 8 + ql]);
        } else {
            bfrag = f16x8{(__fp16)0.f, (__fp16)0.f, (__fp16)0.f, (__fp16)0.f,
                          (__fp16)0.f, (__fp16)0.f, (__fp16)0.f, (__fp16)0.f};
        }
        #pragma unroll
        for (int m = 0; m < 16; ++m) {
            const f16x8 afrag = ap[(kt * 16 + m) * 64 + lane];
            acc[m] = __builtin_amdgcn_mfma_f32_16x16x32_f16(afrag, bfrag, acc[m], 0, 0, 0);
        }
    }
    __syncthreads();   // xs dead; shu region becomes bb (then vjlds last-it)

    // ---- routing iteration body (first/lastit fold to constants when
    //      called from the unrolled routings==3 specialization) ----
    auto routing_iter = [&](bool first, bool lastit) {
        f32x4 cw4[4];
        if (!first) {
            // softmax over co: 1024 items, item i -> row=i>>4 (= n), co=i&15
            #pragma unroll
            for (int k2 = 0; k2 < 4; ++k2) {
                const int i   = t + 256 * k2;
                const int idx = (i >> 4) * 17 + (i & 15);
                const float bv = bb[idx] + bb[BBO + idx];   // sum g01 + g23
                const float mx = rmax16(bv);
                const float e  = __expf(bv - mx);
                const float sd = rsum16(e);
                ccl[(i >> 4) * 20 + (i & 15)] = e * __builtin_amdgcn_rcpf(sd);
            }
            __syncthreads();   // after this, bb is dead in lastit -> vjlds ok
            const f32x4* cwp = reinterpret_cast<const f32x4*>(&ccl[n * 20]);
            cw4[0] = cwp[0]; cw4[1] = cwp[1]; cw4[2] = cwp[2]; cw4[3] = cwp[3];
        }

        #pragma unroll
        for (int m = 0; m < 16; ++m) {
            const float cw = first ? 0.0625f : cw4[m >> 2][m & 3];
            float s0 = cw * acc[m][0], s1 = cw * acc[m][1];
            float s2 = cw * acc[m][2], s3 = cw * acc[m][3];
            // sum over ci (lane bits 0..2): xor1, xor2, half-mirror
            s0 = dppadd<0xB1>(s0);  s1 = dppadd<0xB1>(s1);
            s2 = dppadd<0xB1>(s2);  s3 = dppadd<0xB1>(s3);
            s0 = dppadd<0x4E>(s0);  s1 = dppadd<0x4E>(s1);
            s2 = dppadd<0x4E>(s2);  s3 = dppadd<0x4E>(s3);
            s0 = dppadd<0x141>(s0); s1 = dppadd<0x141>(s1);
            s2 = dppadd<0x141>(s2); s3 = dppadd<0x141>(s3);
            const f32x4 b4 = *reinterpret_cast<const f32x4*>(&bl[m * 16 + g * 4]);
            s0 += b4[0]; s1 += b4[1]; s2 += b4[2]; s3 += b4[3];
            // squash: n2 over po = 4 local r + xor16 + xor32 (R10-proven)
            float q2 = s0 * s0 + s1 * s1 + s2 * s2 + s3 * s3;
            q2 += swz_xor16(q2);
            q2 += __shfl_xor(q2, 32, 64);
            const float sc = __fsqrt_rn(q2) * __builtin_amdgcn_rcpf(1.f + q2);
            const float v0 = s0 * sc, v1 = s1 * sc, v2 = s2 * sc, v3 = s3 * sc;
            if (!lastit) {
                float uu = acc[m][0] * v0 + acc[m][1] * v1
                         + acc[m][2] * v2 + acc[m][3] * v3;
                uu += swz_xor16(uu);          // pair partial: (g0+g1) | (g2+g3)
                if ((g & 1) == 0) {           // g=0 -> slot 0, g=2 -> slot 1
                    const int idx = (g << 9) + (g << 5) + n * 17 + m; // g/2*1088
                    if (first) bb[idx] = uu;  // bij was 0
                    else       bb[idx] += uu;
                }
            } else if (ci_ == 0) {
                const int oc = m * 16 + g * 4;
                vjlds[(oc + 0) * 11 + p_] = v0;
                vjlds[(oc + 1) * 11 + p_] = v1;
                vjlds[(oc + 2) * 11 + p_] = v2;
                vjlds[(oc + 3) * 11 + p_] = v3;
            }
        }
        __syncthreads();
    };

    if (routings == 3) {           // compile-time-folded iteration flags
        routing_iter(true,  false);
        routing_iter(false, false);
        routing_iter(false, true);
    } else {
        for (int it = 0; it < routings; ++it)
            routing_iter(it == 0, it + 1 >= routings);
    }

    // ---- dense output: thread t = oc, 8 wo ----
    float o[8];
    #pragma unroll
    for (int j = 0; j < 8; ++j) o[j] = vjlds[t * 11 + j];
    float* op = out + ((size_t)(b * 256 + t)) * (H * Wd) + ho * Wd + wo0;
    *reinterpret_cast<float4*>(op)     = make_float4(o[0], o[1], o[2], o[3]);
    *reinterpret_cast<float4*>(op + 4) = make_float4(o[4], o[5], o[6], o[7]);
}

extern "C" void kernel_launch(void* const* d_in, const int* in_sizes, int n_in,
                              void* d_out, int out_size, void* d_ws, size_t ws_size,
                              hipStream_t stream) {
    const float* x       = (const float*)d_in[0];
    const float* w       = (const float*)d_in[1];
    const float* biases  = (const float*)d_in[2];
    const int*   routing = (const int*)d_in[3];
    float* out = (float*)d_out;
    __fp16* wf = (__fp16*)d_ws;   // needs 81920 B

    hipLaunchKernelGGL(prep_wfrag, dim3(20), dim3(256), 0, stream, w, wf);
    hipLaunchKernelGGL(convcaps_mfma, dim3(8 * 64 * (64 / TP)), dim3(256), 0, stream,
                       x, wf, biases, routing, out);
}

// Round 17
// 104.411 us; speedup vs baseline: 1.5670x; 1.0457x over previous
//
#include <hip/hip_runtime.h>

// ConvCaps via MFMA: per block (b, ho, 8 wo), votes = W[256 oc x 144 k] *
// X_im2col[144 k x 64 n], n = p*8+ci, k = (kh*3+kw)*16 + pi (padded to 160).
// mfma_f32_16x16x32_f16, fp32 accumulate. Prep kernel writes fp16 A-frags
// (80 KB) to d_ws once per call; all blocks stream them from L2.
// WAVE = N-TILE (R14 LESSON: waves splitting M regressed 28% — all 4 waves
// reading the SAME A-frags makes L1 a free broadcast).
// B-frag = ONE aligned ds_read_b128 from xs: layout xs[ci][r][c][q] (q = pi
// pair innermost, h2 units), per-ci stride 244 words -> 8 ci lanes, 8 banks.
// Staging: one thread per (ci,r,q) unit; 2x float4 + 2 edge scalars.
// Routing in MFMA C-layout: lane=(p,ci), regs=[co=m][po=g*4+r].
//   it-0: cij = 1/16 folded OUT of the DPP tree (reduce raw acc, then
//     s = fma(1/16, red, bias)) — bb pure-written.
//   softmax (it>=1): NO max-subtraction (bij bounded |bv|<~5, exp safe in
//     fp32); 1024 items over 256 threads, DPP row_ror sum only.
//   ci-sum: DPP quad_perm xor1 (0xB1), xor2 (0x4E), half-mirror (0x141)
//   q2 po-sum: ds_swizzle xor16 (0x401F) + __shfl_xor 32  [permlane*_swap
//     REFUTED on HW twice: R11/R12]
//   uu (non-last): v0..v3 never formed — uu = sc*(acc . s); swz_xor16 only;
//     g=0/g=2 lanes write pair-partials to bb0/bb1, softmax sums slots.
//   ccl: stride 20 (80B rows) -> cij read as 4x ds_read_b128.
// R16: __launch_bounds__(256,4) (64 VGPR + 64 AGPR = exact 4-wave budget);
//   routings==3 fully unrolled with compile-time first/last flags.
// LDS overlay: shu = xs (GEMM) -> bb0|bb1 (softmax) -> vjlds (last-it out).

namespace {
constexpr int CI = 8, PIn = 16, H = 64, Wd = 64;
constexpr int TP = 8;          // wo pixels per block
constexpr int NQ = 8;          // pi pairs in x patch
constexpr int CIW = 244;       // per-ci stride in h2 units (3*10*8=240 + 4 pad)
constexpr int KT = 5;          // K tiles of 32 (K=160, 144 real)
constexpr int BBO = 1088;      // bb slot offset (64*17)
}

typedef __fp16 h2  __attribute__((ext_vector_type(2)));
typedef __fp16 f16x8 __attribute__((ext_vector_type(8)));
typedef float  f32x4 __attribute__((ext_vector_type(4)));

__device__ __forceinline__ h2 pkh(float a, float b) {
#if __has_builtin(__builtin_amdgcn_cvt_pkrtz)
    return __builtin_amdgcn_cvt_pkrtz(a, b);
#else
    h2 r; r[0] = (__fp16)a; r[1] = (__fp16)b; return r;
#endif
}

template<int CTRL>
__device__ __forceinline__ float dppmovf(float x) {
    return __builtin_bit_cast(float,
        __builtin_amdgcn_mov_dpp(__builtin_bit_cast(int, x), CTRL, 0xf, 0xf, true));
}
template<int CTRL>
__device__ __forceinline__ float dppadd(float x) { return x + dppmovf<CTRL>(x); }

__device__ __forceinline__ float rsum16(float x) {   // over 16-lane row
    x += dppmovf<0x121>(x); x += dppmovf<0x122>(x);
    x += dppmovf<0x124>(x); x += dppmovf<0x128>(x);
    return x;
}
__device__ __forceinline__ float swz_xor16(float x) {
    return __builtin_bit_cast(float,
        __builtin_amdgcn_ds_swizzle(__builtin_bit_cast(int, x), 0x401F));
}

// ---- prep: conv_w (fp32 OIHW [256][16][3][3]) -> fp16 A-frags in ws ----
// frag f = (kt*16 + m): lane l holds A[oc = m*16 + (l&15)][k = kt*32 + (l>>4)*8 + j]
__global__ __launch_bounds__(256)
void prep_wfrag(const float* __restrict__ w, __fp16* __restrict__ wf) {
    const int gid = blockIdx.x * 256 + threadIdx.x;
    if (gid >= KT * 16 * 64) return;
    const int l = gid & 63, m = (gid >> 6) & 15, kt = gid >> 10;
    const int oc = m * 16 + (l & 15);
    h2* dp = reinterpret_cast<h2*>(wf + (size_t)gid * 8);
    #pragma unroll
    for (int jw = 0; jw < 4; ++jw) {
        const int k0 = kt * 32 + (l >> 4) * 8 + jw * 2;
        float f0 = 0.f, f1 = 0.f;
        if (k0 < 144)     f0 = w[oc * 144 + (k0 & 15) * 9 + (k0 >> 4)];
        if (k0 + 1 < 144) f1 = w[oc * 144 + ((k0 + 1) & 15) * 9 + ((k0 + 1) >> 4)];
        dp[jw] = pkh(f0, f1);
    }
}

__global__ __launch_bounds__(256, 4)
void convcaps_mfma(const float* __restrict__ x,
                   const __fp16* __restrict__ wf,
                   const float* __restrict__ biases,
                   const int* __restrict__ routings_p,
                   float* __restrict__ out)
{
    const int t    = threadIdx.x;
    const int lane = t & 63;
    const int wv   = t >> 6;          // wave = ntile
    const int g    = lane >> 4;       // 0..3
    const int nl   = lane & 15;
    const int n    = wv * 16 + nl;    // 0..63 = p*8 + ci
    const int p_   = n >> 3, ci_ = n & 7;
    const int gh   = g >> 1;          // r9 = 2*kt + gh
    const int ql   = (g & 1) * 4;     // q base for B-frag

    const int blk  = (blockIdx.x & 7) * 512 + (blockIdx.x >> 3);
    const int wseg = blk & 7;
    const int ho   = (blk >> 3) & 63;
    const int b    = blk >> 9;
    const int wo0  = wseg * TP;
    const int routings = routings_p[0];

    // shu overlay: xs (staging+GEMM) -> bb0|bb1 (softmax) -> vjlds (last-it out)
    __shared__ float  shu[2816];                  // 11264 B
    alignas(16) __shared__ float ccl[64 * 20];    // 5120 B cij [n][co] stride 20
    __shared__ float  bl[256];                    // biases
    h2*    xs    = reinterpret_cast<h2*>(shu);    // [ci][r][c][q], CIW words/ci
    float* bb    = shu;                           // bij partials: [slot][n*17+m]
    float* vjlds = shu;                           // [oc][p] stride 11

    // ---- stage x patch: one thread per (ci, r, q); 2x float4 + 2 edges ----
    if (t < 192) {
        const int ci  = t / 24;
        const int rem = t - ci * 24;
        const int r   = rem >> 3, q = rem & 7;
        const int hy  = ho - 1 + r;
        const bool rowok = (hy >= 0) && (hy < H);
        const float* row0 = x + (((size_t)(b * CI + ci) * PIn + 2 * q) * H + hy) * Wd;
        const float* row1 = row0 + H * Wd;
        float4 m0a = {0,0,0,0}, m1a = {0,0,0,0}, m0b = {0,0,0,0}, m1b = {0,0,0,0};
        float  e0a = 0.f, e0b = 0.f, e9a = 0.f, e9b = 0.f;
        if (rowok) {
            m0a = *reinterpret_cast<const float4*>(row0 + wo0);
            m1a = *reinterpret_cast<const float4*>(row0 + wo0 + 4);
            m0b = *reinterpret_cast<const float4*>(row1 + wo0);
            m1b = *reinterpret_cast<const float4*>(row1 + wo0 + 4);
            if (wo0 > 0)       { e0a = row0[wo0 - 1]; e0b = row1[wo0 - 1]; }
            if (wo0 + 8 < Wd)  { e9a = row0[wo0 + 8]; e9b = row1[wo0 + 8]; }
        }
        h2* xr = &xs[ci * CIW + (r * 10) * 8 + q];   // c stride = 8 h2 units
        xr[0 * 8] = pkh(e0a, e0b);
        xr[1 * 8] = pkh(m0a.x, m0b.x);
        xr[2 * 8] = pkh(m0a.y, m0b.y);
        xr[3 * 8] = pkh(m0a.z, m0b.z);
        xr[4 * 8] = pkh(m0a.w, m0b.w);
        xr[5 * 8] = pkh(m1a.x, m1b.x);
        xr[6 * 8] = pkh(m1a.y, m1b.y);
        xr[7 * 8] = pkh(m1a.z, m1b.z);
        xr[8 * 8] = pkh(m1a.w, m1b.w);
        xr[9 * 8] = pkh(e9a, e9b);
    }
    bl[t] = biases[t];
    __syncthreads();

    // ---- GEMM: acc[m] = votes[oc = m*16+g*4+r][n]; B = one b128 from xs ----
    f32x4 acc[16];
    #pragma unroll
    for (int m = 0; m < 16; ++m) acc[m] = f32x4{0.f, 0.f, 0.f, 0.f};

    const f16x8* ap = reinterpret_cast<const f16x8*>(wf);
    #pragma unroll
    for (int kt = 0; kt < KT; ++kt) {
        f16x8 bfrag;
        const int k0 = kt * 32 + g * 8;
        if (k0 < 144) {
            const int r9 = 2 * kt + gh;
            const int kh = (r9 * 11) >> 5;        // r9/3 for r9<=8
            const int kw = r9 - 3 * kh;
            bfrag = *reinterpret_cast<const f16x8*>(
                &xs[ci_ * CIW + (kh * 10 + p_ + kw) * 8 + ql]);
        } else {
            bfrag = f16x8{(__fp16)0.f, (__fp16)0.f, (__fp16)0.f, (__fp16)0.f,
                          (__fp16)0.f, (__fp16)0.f, (__fp16)0.f, (__fp16)0.f};
        }
        #pragma unroll
        for (int m = 0; m < 16; ++m) {
            const f16x8 afrag = ap[(kt * 16 + m) * 64 + lane];
            acc[m] = __builtin_amdgcn_mfma_f32_16x16x32_f16(afrag, bfrag, acc[m], 0, 0, 0);
        }
    }
    __syncthreads();   // xs dead; shu region becomes bb (then vjlds last-it)

    // ---- routing iteration body (first/lastit fold to constants when
    //      called from the unrolled routings==3 specialization) ----
    auto routing_iter = [&](bool first, bool lastit) {
        f32x4 cw4[4];
        if (!first) {
            // softmax over co (no max-sub: |bv| < ~5, exp safe in fp32)
            #pragma unroll
            for (int k2 = 0; k2 < 4; ++k2) {
                const int i   = t + 256 * k2;
                const int idx = (i >> 4) * 17 + (i & 15);
                const float bv = bb[idx] + bb[BBO + idx];   // sum g01 + g23
                const float e  = __expf(bv);
                const float sd = rsum16(e);
                ccl[(i >> 4) * 20 + (i & 15)] = e * __builtin_amdgcn_rcpf(sd);
            }
            __syncthreads();   // after this, bb is dead in lastit -> vjlds ok
            const f32x4* cwp = reinterpret_cast<const f32x4*>(&ccl[n * 20]);
            cw4[0] = cwp[0]; cw4[1] = cwp[1]; cw4[2] = cwp[2]; cw4[3] = cwp[3];
        }

        #pragma unroll
        for (int m = 0; m < 16; ++m) {
            float s0, s1, s2, s3;
            if (first) {      // cij = 1/16 folded out of the DPP tree
                s0 = acc[m][0]; s1 = acc[m][1]; s2 = acc[m][2]; s3 = acc[m][3];
            } else {
                const float cw = cw4[m >> 2][m & 3];
                s0 = cw * acc[m][0]; s1 = cw * acc[m][1];
                s2 = cw * acc[m][2]; s3 = cw * acc[m][3];
            }
            // sum over ci (lane bits 0..2): xor1, xor2, half-mirror
            s0 = dppadd<0xB1>(s0);  s1 = dppadd<0xB1>(s1);
            s2 = dppadd<0xB1>(s2);  s3 = dppadd<0xB1>(s3);
            s0 = dppadd<0x4E>(s0);  s1 = dppadd<0x4E>(s1);
            s2 = dppadd<0x4E>(s2);  s3 = dppadd<0x4E>(s3);
            s0 = dppadd<0x141>(s0); s1 = dppadd<0x141>(s1);
            s2 = dppadd<0x141>(s2); s3 = dppadd<0x141>(s3);
            const f32x4 b4 = *reinterpret_cast<const f32x4*>(&bl[m * 16 + g * 4]);
            if (first) {
                s0 = fmaf(0.0625f, s0, b4[0]); s1 = fmaf(0.0625f, s1, b4[1]);
                s2 = fmaf(0.0625f, s2, b4[2]); s3 = fmaf(0.0625f, s3, b4[3]);
            } else {
                s0 += b4[0]; s1 += b4[1]; s2 += b4[2]; s3 += b4[3];
            }
            // squash: n2 over po = 4 local r + xor16 + xor32 (R10-proven)
            float q2 = s0 * s0 + s1 * s1 + s2 * s2 + s3 * s3;
            q2 += swz_xor16(q2);
            q2 += __shfl_xor(q2, 32, 64);
            const float sc = __fsqrt_rn(q2) * __builtin_amdgcn_rcpf(1.f + q2);
            if (!lastit) {
                // v never formed: uu = sc * (acc . s)
                float dot = acc[m][0] * s0 + acc[m][1] * s1
                          + acc[m][2] * s2 + acc[m][3] * s3;
                float uu = dot * sc;
                uu += swz_xor16(uu);          // pair partial: (g0+g1) | (g2+g3)
                if ((g & 1) == 0) {           // g=0 -> slot 0, g=2 -> slot 1
                    const int idx = (g << 9) + (g << 5) + n * 17 + m; // g/2*1088
                    if (first) bb[idx] = uu;  // bij was 0
                    else       bb[idx] += uu;
                }
            } else if (ci_ == 0) {
                const int oc = m * 16 + g * 4;
                vjlds[(oc + 0) * 11 + p_] = s0 * sc;
                vjlds[(oc + 1) * 11 + p_] = s1 * sc;
                vjlds[(oc + 2) * 11 + p_] = s2 * sc;
                vjlds[(oc + 3) * 11 + p_] = s3 * sc;
            }
        }
        __syncthreads();
    };

    if (routings == 3) {           // compile-time-folded iteration flags
        routing_iter(true,  false);
        routing_iter(false, false);
        routing_iter(false, true);
    } else {
        for (int it = 0; it < routings; ++it)
            routing_iter(it == 0, it + 1 >= routings);
    }

    // ---- dense output: thread t = oc, 8 wo ----
    float o[8];
    #pragma unroll
    for (int j = 0; j < 8; ++j) o[j] = vjlds[t * 11 + j];
    float* op = out + ((size_t)(b * 256 + t)) * (H * Wd) + ho * Wd + wo0;
    *reinterpret_cast<float4*>(op)     = make_float4(o[0], o[1], o[2], o[3]);
    *reinterpret_cast<float4*>(op + 4) = make_float4(o[4], o[5], o[6], o[7]);
}

extern "C" void kernel_launch(void* const* d_in, const int* in_sizes, int n_in,
                              void* d_out, int out_size, void* d_ws, size_t ws_size,
                              hipStream_t stream) {
    const float* x       = (const float*)d_in[0];
    const float* w       = (const float*)d_in[1];
    const float* biases  = (const float*)d_in[2];
    const int*   routing = (const int*)d_in[3];
    float* out = (float*)d_out;
    __fp16* wf = (__fp16*)d_ws;   // needs 81920 B

    hipLaunchKernelGGL(prep_wfrag, dim3(20), dim3(256), 0, stream, w, wf);
    hipLaunchKernelGGL(convcaps_mfma, dim3(8 * 64 * (64 / TP)), dim3(256), 0, stream,
                       x, wf, biases, routing, out);
}